// Round 1
// baseline (2998.720 us; speedup 1.0000x reference)
//
#include <hip/hip_runtime.h>

#define DD 48
#define HHH 48
#define WWW 48
#define HWQ (HHH*WWW)         // 2304
#define QQ (DD*HHH*WWW)       // 110592
#define NK 7

// ---------------- weight re-layout: w[o][i][tap] -> w2[tap][i][o] ----------------
__global__ __launch_bounds__(256) void prep_weights(const float* __restrict__ w_in,
                                                    const float* __restrict__ w_out,
                                                    float* __restrict__ w2a,
                                                    float* __restrict__ w2b) {
    int idx = blockIdx.x * 256 + threadIdx.x;
    const int n1 = 64 * 32 * 27;
    const int n2 = 64 * 64 * 27;
    if (idx < n1) {
        int o = idx / (32 * 27);
        int rem = idx % (32 * 27);
        int i = rem / 27, tap = rem % 27;
        w2a[(tap * 32 + i) * 64 + o] = w_in[idx];
    } else if (idx < n1 + n2) {
        int j = idx - n1;
        int o = j / (64 * 27);
        int rem = j % (64 * 27);
        int i = rem / 27, tap = rem % 27;
        w2b[(tap * 64 + i) * 64 + o] = w_out[j];
    }
}

// ---------------- direct 3D conv, pad=1, k=3. lane = out-channel o ----------------
// grid (48 z, 12 ytiles, B); block 256 = 4 waves, wave w -> y row (ytile*4+w).
// Bias is skipped: InstanceNorm subtracts the per-(b,c) mean, so conv bias cancels.
template<int CIN>
__global__ __launch_bounds__(256) void conv3d_k(const float* __restrict__ xin,
                                                const float* __restrict__ w2,
                                                float* __restrict__ yout) {
    __shared__ alignas(16) float plane[32 * 6 * 52];
    const int z = blockIdx.x;
    const int ytile = blockIdx.y;
    const int b = blockIdx.z;
    const int tid = threadIdx.x;
    const int o = tid & 63;
    const int w = tid >> 6;
    const int y = ytile * 4 + w;

    float acc[48];
    #pragma unroll
    for (int xx = 0; xx < 48; xx++) acc[xx] = 0.f;

    for (int ic = 0; ic < CIN / 32; ic++) {
        for (int dz = 0; dz < 3; dz++) {
            __syncthreads();
            int z_in = z + dz - 1;
            for (int idx = tid; idx < 32 * 6 * 50; idx += 256) {
                int il = idx / 300;
                int rem = idx % 300;
                int yy = rem / 50;
                int xs = rem % 50;
                int yg = ytile * 4 + yy - 1;
                int xg = xs - 1;
                float v = 0.f;
                if (z_in >= 0 && z_in < DD && yg >= 0 && yg < HHH && xg >= 0 && xg < WWW)
                    v = xin[(((size_t)b * CIN + ic * 32 + il) * DD + z_in) * HWQ + yg * WWW + xg];
                plane[(il * 6 + yy) * 52 + xs] = v;
            }
            __syncthreads();
            for (int il = 0; il < 32; il++) {
                int i = ic * 32 + il;
                #pragma unroll
                for (int dy = 0; dy < 3; dy++) {
                    const float4* rp = reinterpret_cast<const float4*>(&plane[(il * 6 + (w + dy)) * 52]);
                    float rv[52];
                    #pragma unroll
                    for (int r = 0; r < 13; r++) {
                        float4 v4 = rp[r];
                        rv[4*r+0] = v4.x; rv[4*r+1] = v4.y; rv[4*r+2] = v4.z; rv[4*r+3] = v4.w;
                    }
                    int tapbase = (dz * 3 + dy) * 3;
                    float wa = w2[((tapbase + 0) * CIN + i) * 64 + o];
                    float wb = w2[((tapbase + 1) * CIN + i) * 64 + o];
                    float wc = w2[((tapbase + 2) * CIN + i) * 64 + o];
                    #pragma unroll
                    for (int xx = 0; xx < 48; xx++)
                        acc[xx] += rv[xx] * wa + rv[xx + 1] * wb + rv[xx + 2] * wc;
                }
            }
        }
    }
    float4* op = reinterpret_cast<float4*>(&yout[(((size_t)b * 64 + o) * DD + z) * HWQ + y * WWW]);
    #pragma unroll
    for (int r = 0; r < 12; r++) {
        float4 v;
        v.x = acc[4*r]; v.y = acc[4*r+1]; v.z = acc[4*r+2]; v.w = acc[4*r+3];
        op[r] = v;
    }
}

// ---------------- InstanceNorm: stats (one block per (b,c), deterministic tree) ----------------
__global__ __launch_bounds__(256) void inorm_stats(const float* __restrict__ x, float2* __restrict__ st) {
    __shared__ float ssum[256], ssq[256];
    const int bc = blockIdx.x;
    const float4* p = reinterpret_cast<const float4*>(x + (size_t)bc * QQ);
    float s = 0.f, q2 = 0.f;
    for (int idx = threadIdx.x; idx < QQ / 4; idx += 256) {
        float4 v = p[idx];
        s  += v.x + v.y + v.z + v.w;
        q2 += v.x * v.x + v.y * v.y + v.z * v.z + v.w * v.w;
    }
    ssum[threadIdx.x] = s; ssq[threadIdx.x] = q2;
    __syncthreads();
    for (int off = 128; off > 0; off >>= 1) {
        if (threadIdx.x < off) {
            ssum[threadIdx.x] += ssum[threadIdx.x + off];
            ssq[threadIdx.x]  += ssq[threadIdx.x + off];
        }
        __syncthreads();
    }
    if (threadIdx.x == 0) {
        float mean = ssum[0] / (float)QQ;
        float var = ssq[0] / (float)QQ - mean * mean;
        st[bc] = make_float2(mean, rsqrtf(var + 1e-5f));
    }
}

__global__ __launch_bounds__(256) void inorm_apply(const float* __restrict__ x, const float2* __restrict__ st,
                                                   float* __restrict__ y) {
    const int bc = blockIdx.y;
    float2 mv = st[bc];
    int idx = blockIdx.x * 256 + threadIdx.x;      // float4 index, grid.x*256 == QQ/4 exactly
    float4 v = reinterpret_cast<const float4*>(x + (size_t)bc * QQ)[idx];
    v.x = fmaxf((v.x - mv.x) * mv.y, 0.f);
    v.y = fmaxf((v.y - mv.x) * mv.y, 0.f);
    v.z = fmaxf((v.z - mv.x) * mv.y, 0.f);
    v.w = fmaxf((v.w - mv.x) * mv.y, 0.f);
    reinterpret_cast<float4*>(y + (size_t)bc * QQ)[idx] = v;
}

// ---------------- k-means ----------------
__global__ __launch_bounds__(256) void init_cent(const float* __restrict__ x1, float* __restrict__ cent) {
    int t = blockIdx.x * 256 + threadIdx.x;
    if (t < 2 * NK * 64) {
        int b = t / 448, r = t % 448, k = r / 64, c = r % 64;
        cent[t] = x1[((size_t)b * 64 + c) * QQ + k];
    }
}

// 128 threads, 128 points per block; feat tile [64ch][128pt] in LDS (pad 129).
template<bool WP>
__global__ __launch_bounds__(128) void km_assign(const float* __restrict__ x1, const float* __restrict__ cent,
                                                 int* __restrict__ labels, float* __restrict__ part) {
    __shared__ float tile[64 * 129];
    __shared__ float cs[448];
    __shared__ float c2s[NK];
    __shared__ int labs[128];
    const int b = blockIdx.y;
    const int q0 = blockIdx.x * 128;
    const int t = threadIdx.x;

    for (int idx = t; idx < 448; idx += 128) cs[idx] = cent[b * 448 + idx];
    for (int r = 0; r < 64; r++) tile[r * 129 + t] = x1[((size_t)b * 64 + r) * QQ + q0 + t];
    __syncthreads();
    if (t < NK) {
        float s = 0.f;
        for (int c = 0; c < 64; c++) s += cs[t * 64 + c] * cs[t * 64 + c];
        c2s[t] = s;
    }
    __syncthreads();

    float d[NK];
    #pragma unroll
    for (int k = 0; k < NK; k++) d[k] = 0.f;
    for (int c = 0; c < 64; c++) {
        float xv = tile[c * 129 + t];
        #pragma unroll
        for (int k = 0; k < NK; k++) d[k] += xv * cs[k * 64 + c];
    }
    int lab = 0;
    float best = c2s[0] - 2.f * d[0];
    #pragma unroll
    for (int k = 1; k < NK; k++) {
        float dd = c2s[k] - 2.f * d[k];
        if (dd < best) { best = dd; lab = k; }   // strict <  => first-min, matches argmin
    }
    labels[(size_t)b * QQ + q0 + t] = lab;
    labs[t] = lab;

    if (WP) {
        __syncthreads();
        int c = t & 63, g = t >> 6;
        float s[NK], cn[NK];
        #pragma unroll
        for (int k = 0; k < NK; k++) { s[k] = 0.f; cn[k] = 0.f; }
        for (int j = 0; j < 64; j++) {
            int l = labs[g * 64 + j];
            float v = tile[c * 129 + g * 64 + j];
            #pragma unroll
            for (int k = 0; k < NK; k++) {
                bool m = (l == k);
                s[k]  += m ? v : 0.f;
                cn[k] += m ? 1.f : 0.f;
            }
        }
        float* pb = part + (((size_t)b * 864 + blockIdx.x) * 2 + g) * 456;
        #pragma unroll
        for (int k = 0; k < NK; k++) pb[k * 64 + c] = s[k];
        if (c == 0) {
            #pragma unroll
            for (int k = 0; k < NK; k++) pb[448 + k] = cn[k];
        }
    }
}

__global__ __launch_bounds__(1024) void km_update(const float* __restrict__ part, float* __restrict__ cent) {
    int t = threadIdx.x;
    if (t >= 896) return;
    int b = t / 448, r = t % 448, k = r / 64;
    float s = 0.f, cn = 0.f;
    const float* pb = part + (size_t)b * 1728 * 456;
    for (int p = 0; p < 1728; p++) {
        s  += pb[p * 456 + r];
        cn += pb[p * 456 + 448 + k];
    }
    float oldc = cent[t];
    cent[t] = (cn > 0.f) ? (s / fmaxf(cn, 1.f)) : oldc;
}

// ---------------- centroid MLPs -> WkT[b][k][i][o], bias2[b][k][o] ----------------
__global__ __launch_bounds__(256) void mlp_kernel(const float* __restrict__ cent,
        const float* __restrict__ kW1, const float* __restrict__ kb1,
        const float* __restrict__ kW2, const float* __restrict__ kb2,
        const float* __restrict__ bW1, const float* __restrict__ bb1,
        const float* __restrict__ bW2, const float* __restrict__ bb2,
        const float* __restrict__ w_mat, float* __restrict__ WkT, float* __restrict__ bias2) {
    __shared__ float cr[64];
    __shared__ float hid[256];
    __shared__ float vout[64];
    const int bk = blockIdx.x;            // (b*7 + k)
    const int t = threadIdx.x;
    if (t < 64) cr[t] = cent[bk * 64 + t];
    __syncthreads();
    // kernel branch: sigmoid(relu(c@kW1+kb1)@kW2+kb2)
    float h = kb1[t];
    for (int c = 0; c < 64; c++) h += cr[c] * kW1[c * 256 + t];
    hid[t] = fmaxf(h, 0.f);
    __syncthreads();
    if (t < 64) {
        float s = kb2[t];
        for (int j = 0; j < 256; j++) s += hid[j] * kW2[j * 64 + t];
        vout[t] = 1.f / (1.f + expf(-s));
    }
    __syncthreads();
    for (int idx = t; idx < 4096; idx += 256) {
        int i = idx >> 6, o = idx & 63;
        WkT[(size_t)bk * 4096 + idx] = vout[i] * w_mat[o * 64 + i];
    }
    __syncthreads();
    // bias branch: relu(c@bW1+bb1)@bW2+bb2
    float h2 = bb1[t];
    for (int c = 0; c < 64; c++) h2 += cr[c] * bW1[c * 256 + t];
    hid[t] = fmaxf(h2, 0.f);
    __syncthreads();
    if (t < 64) {
        float s = bb2[t];
        for (int j = 0; j < 256; j++) s += hid[j] * bW2[j * 64 + t];
        bias2[bk * 64 + t] = s;
    }
}

// ---------------- label-gated matvec + bias + shortcut ----------------
// out2[b,o,q] = sum_i WkT[b,lab(q)][i][o] * x1[b,i,q] + bias2[b,lab(q),o] + x1[b,o,q]
__global__ __launch_bounds__(256) void scatter_mm(const float* __restrict__ x1, const int* __restrict__ labels,
                                                  const float* __restrict__ WkT, const float* __restrict__ bias2,
                                                  float* __restrict__ out2) {
    __shared__ float xt[64 * 66];
    __shared__ float os[64 * 66];
    __shared__ int labs[64];
    const int b = blockIdx.y;
    const int q0 = blockIdx.x * 64;
    const int t = threadIdx.x;
    const int lane = t & 63;
    for (int r = t >> 6; r < 64; r += 4)
        xt[r * 66 + lane] = x1[((size_t)b * 64 + r) * QQ + q0 + lane];
    if (t < 64) labs[t] = labels[(size_t)b * QQ + q0 + t];
    __syncthreads();
    const int o = lane;
    const int wq = (t >> 6) * 16;
    for (int qi = 0; qi < 16; qi++) {
        int q = wq + qi;
        int l = labs[q];
        const float* Wp = WkT + ((size_t)(b * 7 + l) << 12);
        float acc = bias2[(b * 7 + l) * 64 + o] + xt[o * 66 + q];
        for (int i = 0; i < 64; i++)
            acc += Wp[i * 64 + o] * xt[i * 66 + q];
        os[o * 66 + q] = acc;
    }
    __syncthreads();
    for (int r = t >> 6; r < 64; r += 4)
        out2[((size_t)b * 64 + r) * QQ + q0 + lane] = os[r * 66 + lane];
}

extern "C" void kernel_launch(void* const* d_in, const int* in_sizes, int n_in,
                              void* d_out, int out_size, void* d_ws, size_t ws_size,
                              hipStream_t stream) {
    const float* x     = (const float*)d_in[0];
    const float* w_in  = (const float*)d_in[1];
    // d_in[2] = b_in : cancelled by InstanceNorm (mean-shift invariance)
    const float* w_mat = (const float*)d_in[3];
    const float* kW1   = (const float*)d_in[4];
    const float* kb1   = (const float*)d_in[5];
    const float* kW2   = (const float*)d_in[6];
    const float* kb2   = (const float*)d_in[7];
    const float* bW1   = (const float*)d_in[8];
    const float* bb1   = (const float*)d_in[9];
    const float* bW2   = (const float*)d_in[10];
    const float* bb2   = (const float*)d_in[11];
    const float* w_out = (const float*)d_in[12];
    // d_in[13] = b_out : cancelled by InstanceNorm
    float* out = (float*)d_out;

    char* ws = (char*)d_ws;
    size_t off = 0;
    auto alloc = [&](size_t bytes) { void* p = ws + off; off = (off + bytes + 255) & ~255UL; return p; };
    float* buf0  = (float*)alloc((size_t)2 * 64 * QQ * 4);     // conv raw / out2
    float* buf1  = (float*)alloc((size_t)2 * 64 * QQ * 4);     // x1 (normed)
    float* w2a   = (float*)alloc(27 * 32 * 64 * 4);
    float* w2b   = (float*)alloc(27 * 64 * 64 * 4);
    float* cent  = (float*)alloc(2 * 448 * 4);
    float* part  = (float*)alloc((size_t)2 * 1728 * 456 * 4);
    int*   labels= (int*)  alloc((size_t)2 * QQ * 4);
    float* WkT   = (float*)alloc(2 * 7 * 4096 * 4);
    float* bias2 = (float*)alloc(2 * 448 * 4);
    float2* st   = (float2*)alloc(128 * 8);
    if (off > ws_size) return;  // workspace too small: fail loudly (wrong output) rather than corrupt

    prep_weights<<<648, 256, 0, stream>>>(w_in, w_out, w2a, w2b);
    conv3d_k<32><<<dim3(48, 12, 2), 256, 0, stream>>>(x, w2a, buf0);
    inorm_stats<<<128, 256, 0, stream>>>(buf0, st);
    inorm_apply<<<dim3(108, 128), 256, 0, stream>>>(buf0, st, buf1);

    init_cent<<<4, 256, 0, stream>>>(buf1, cent);
    for (int it = 0; it < 8; it++) {
        km_assign<true><<<dim3(864, 2), 128, 0, stream>>>(buf1, cent, labels, part);
        km_update<<<1, 1024, 0, stream>>>(part, cent);
    }
    km_assign<false><<<dim3(864, 2), 128, 0, stream>>>(buf1, cent, labels, nullptr);

    mlp_kernel<<<14, 256, 0, stream>>>(cent, kW1, kb1, kW2, kb2, bW1, bb1, bW2, bb2, w_mat, WkT, bias2);
    scatter_mm<<<dim3(1728, 2), 256, 0, stream>>>(buf1, labels, WkT, bias2, buf0);

    conv3d_k<64><<<dim3(48, 12, 2), 256, 0, stream>>>(buf0, w2b, out);
    inorm_stats<<<128, 256, 0, stream>>>(out, st);
    inorm_apply<<<dim3(108, 128), 256, 0, stream>>>(out, st, out);
}

// Round 2
// 2187.902 us; speedup vs baseline: 1.3706x; 1.3706x over previous
//
#include <hip/hip_runtime.h>

#define DD 48
#define HHH 48
#define WWW 48
#define HWQ (HHH*WWW)         // 2304
#define QQ (DD*HHH*WWW)       // 110592
#define NK 7

// ---------------- weight re-layout: w[o][i][tap] -> w2[tap][i][o] ----------------
__global__ __launch_bounds__(256) void prep_weights(const float* __restrict__ w_in,
                                                    const float* __restrict__ w_out,
                                                    float* __restrict__ w2a,
                                                    float* __restrict__ w2b) {
    int idx = blockIdx.x * 256 + threadIdx.x;
    const int n1 = 64 * 32 * 27;
    const int n2 = 64 * 64 * 27;
    if (idx < n1) {
        int o = idx / (32 * 27);
        int rem = idx % (32 * 27);
        int i = rem / 27, tap = rem % 27;
        w2a[(tap * 32 + i) * 64 + o] = w_in[idx];
    } else if (idx < n1 + n2) {
        int j = idx - n1;
        int o = j / (64 * 27);
        int rem = j % (64 * 27);
        int i = rem / 27, tap = rem % 27;
        w2b[(tap * 64 + i) * 64 + o] = w_out[j];
    }
}

// ---------------- direct 3D conv, pad=1, k=3. lane = out-channel o ----------------
// grid (48 z, 12 ytiles, B*2): blockIdx.z = b*2 + xhalf. Block 256 = 4 waves,
// wave w -> y row (ytile*4+w); each thread computes 24 x-outputs (one half-row).
// 16-channel LDS tiles (10.75 KB) for ~8 resident blocks/CU.
// Bias skipped: InstanceNorm subtracts the per-(b,c) mean, so conv bias cancels.
template<int CIN>
__global__ __launch_bounds__(256) void conv3d_k(const float* __restrict__ xin,
                                                const float* __restrict__ w2,
                                                float* __restrict__ yout) {
    __shared__ alignas(16) float plane[16 * 6 * 28];
    const int z = blockIdx.x;
    const int ytile = blockIdx.y;
    const int bz = blockIdx.z;
    const int b = bz >> 1, xh = bz & 1;
    const int x0 = xh * 24;
    const int tid = threadIdx.x;
    const int o = tid & 63;
    const int w = tid >> 6;
    const int y = ytile * 4 + w;

    float acc[24];
    #pragma unroll
    for (int xx = 0; xx < 24; xx++) acc[xx] = 0.f;

    for (int ict = 0; ict < CIN / 16; ict++) {
        for (int dz = 0; dz < 3; dz++) {
            __syncthreads();
            int z_in = z + dz - 1;
            for (int idx = tid; idx < 16 * 6 * 26; idx += 256) {
                int il = idx / 156;
                int rem = idx % 156;
                int yy = rem / 26;
                int xs = rem % 26;
                int yg = ytile * 4 + yy - 1;
                int xg = x0 + xs - 1;
                float v = 0.f;
                if (z_in >= 0 && z_in < DD && yg >= 0 && yg < HHH && xg >= 0 && xg < WWW)
                    v = xin[(((size_t)b * CIN + ict * 16 + il) * DD + z_in) * HWQ + yg * WWW + xg];
                plane[(il * 6 + yy) * 28 + xs] = v;
            }
            __syncthreads();
            for (int il = 0; il < 16; il++) {
                int i = ict * 16 + il;
                #pragma unroll
                for (int dy = 0; dy < 3; dy++) {
                    const float4* rp = reinterpret_cast<const float4*>(&plane[(il * 6 + (w + dy)) * 28]);
                    float rv[28];
                    #pragma unroll
                    for (int r = 0; r < 7; r++) {
                        float4 v4 = rp[r];
                        rv[4*r+0] = v4.x; rv[4*r+1] = v4.y; rv[4*r+2] = v4.z; rv[4*r+3] = v4.w;
                    }
                    int tapbase = (dz * 3 + dy) * 3;
                    float wa = w2[((tapbase + 0) * CIN + i) * 64 + o];
                    float wb = w2[((tapbase + 1) * CIN + i) * 64 + o];
                    float wc = w2[((tapbase + 2) * CIN + i) * 64 + o];
                    #pragma unroll
                    for (int xx = 0; xx < 24; xx++)
                        acc[xx] += rv[xx] * wa + rv[xx + 1] * wb + rv[xx + 2] * wc;
                }
            }
        }
    }
    float* obase = &yout[(((size_t)b * 64 + o) * DD + z) * HWQ + y * WWW + x0];
    #pragma unroll
    for (int r = 0; r < 6; r++) {
        float4 v;
        v.x = acc[4*r]; v.y = acc[4*r+1]; v.z = acc[4*r+2]; v.w = acc[4*r+3];
        reinterpret_cast<float4*>(obase)[r] = v;
    }
}

// ---------------- InstanceNorm: stats (one block per (b,c), deterministic tree) ----------------
__global__ __launch_bounds__(256) void inorm_stats(const float* __restrict__ x, float2* __restrict__ st) {
    __shared__ float ssum[256], ssq[256];
    const int bc = blockIdx.x;
    const float4* p = reinterpret_cast<const float4*>(x + (size_t)bc * QQ);
    float s = 0.f, q2 = 0.f;
    for (int idx = threadIdx.x; idx < QQ / 4; idx += 256) {
        float4 v = p[idx];
        s  += v.x + v.y + v.z + v.w;
        q2 += v.x * v.x + v.y * v.y + v.z * v.z + v.w * v.w;
    }
    ssum[threadIdx.x] = s; ssq[threadIdx.x] = q2;
    __syncthreads();
    for (int off = 128; off > 0; off >>= 1) {
        if (threadIdx.x < off) {
            ssum[threadIdx.x] += ssum[threadIdx.x + off];
            ssq[threadIdx.x]  += ssq[threadIdx.x + off];
        }
        __syncthreads();
    }
    if (threadIdx.x == 0) {
        float mean = ssum[0] / (float)QQ;
        float var = ssq[0] / (float)QQ - mean * mean;
        st[bc] = make_float2(mean, rsqrtf(var + 1e-5f));
    }
}

__global__ __launch_bounds__(256) void inorm_apply(const float* __restrict__ x, const float2* __restrict__ st,
                                                   float* __restrict__ y) {
    const int bc = blockIdx.y;
    float2 mv = st[bc];
    int idx = blockIdx.x * 256 + threadIdx.x;      // float4 index, grid.x*256 == QQ/4 exactly
    float4 v = reinterpret_cast<const float4*>(x + (size_t)bc * QQ)[idx];
    v.x = fmaxf((v.x - mv.x) * mv.y, 0.f);
    v.y = fmaxf((v.y - mv.x) * mv.y, 0.f);
    v.z = fmaxf((v.z - mv.x) * mv.y, 0.f);
    v.w = fmaxf((v.w - mv.x) * mv.y, 0.f);
    reinterpret_cast<float4*>(y + (size_t)bc * QQ)[idx] = v;
}

// ---------------- k-means ----------------
__global__ __launch_bounds__(256) void init_cent(const float* __restrict__ x1, float* __restrict__ cent) {
    int t = blockIdx.x * 256 + threadIdx.x;
    if (t < 2 * NK * 64) {
        int b = t / 448, r = t % 448, k = r / 64, c = r % 64;
        cent[t] = x1[((size_t)b * 64 + c) * QQ + k];
    }
}

// 128 threads, 512 points per block (4 chunks of 128); feat tile [64ch][128pt] (pad 129).
// Per-block partials (456 floats: 448 sums + 7 counts + pad) -> part[b][216][456].
template<bool WP>
__global__ __launch_bounds__(128) void km_assign(const float* __restrict__ x1, const float* __restrict__ cent,
                                                 int* __restrict__ labels, float* __restrict__ part) {
    __shared__ float tile[64 * 129];
    __shared__ float cs[448];
    __shared__ float c2s[NK];
    __shared__ int labs[128];
    __shared__ float red[456];
    const int b = blockIdx.y;
    const int Q0 = blockIdx.x * 512;
    const int t = threadIdx.x;
    const int c = t & 63, g = t >> 6;

    for (int idx = t; idx < 448; idx += 128) cs[idx] = cent[b * 448 + idx];
    __syncthreads();
    if (t < NK) {
        float s = 0.f;
        for (int ch = 0; ch < 64; ch++) s += cs[t * 64 + ch] * cs[t * 64 + ch];
        c2s[t] = s;
    }

    float ps[NK], pc[NK];
    #pragma unroll
    for (int k = 0; k < NK; k++) { ps[k] = 0.f; pc[k] = 0.f; }

    for (int cc = 0; cc < 4; cc++) {
        const int q0 = Q0 + cc * 128;
        __syncthreads();   // protect tile/labs reuse across chunks (and c2s on first pass)
        for (int r = 0; r < 64; r++) tile[r * 129 + t] = x1[((size_t)b * 64 + r) * QQ + q0 + t];
        __syncthreads();

        float d[NK];
        #pragma unroll
        for (int k = 0; k < NK; k++) d[k] = 0.f;
        for (int ch = 0; ch < 64; ch++) {
            float xv = tile[ch * 129 + t];
            #pragma unroll
            for (int k = 0; k < NK; k++) d[k] += xv * cs[k * 64 + ch];
        }
        int lab = 0;
        float best = c2s[0] - 2.f * d[0];
        #pragma unroll
        for (int k = 1; k < NK; k++) {
            float dd = c2s[k] - 2.f * d[k];
            if (dd < best) { best = dd; lab = k; }   // strict < => first-min, matches argmin
        }
        labels[(size_t)b * QQ + q0 + t] = lab;

        if (WP) {
            labs[t] = lab;
            __syncthreads();
            for (int j = 0; j < 64; j++) {
                int l = labs[g * 64 + j];
                float v = tile[c * 129 + g * 64 + j];
                #pragma unroll
                for (int k = 0; k < NK; k++) {
                    ps[k] += (l == k) ? v : 0.f;
                    pc[k] += (l == k) ? 1.f : 0.f;
                }
            }
        }
    }

    if (WP) {
        __syncthreads();
        if (g == 0) {
            #pragma unroll
            for (int k = 0; k < NK; k++) red[k * 64 + c] = ps[k];
            if (c == 0) {
                #pragma unroll
                for (int k = 0; k < NK; k++) red[448 + k] = pc[k];
            }
        }
        __syncthreads();
        if (g == 1) {
            #pragma unroll
            for (int k = 0; k < NK; k++) red[k * 64 + c] += ps[k];
            if (c == 0) {
                #pragma unroll
                for (int k = 0; k < NK; k++) red[448 + k] += pc[k];
            }
        }
        __syncthreads();
        float* pb = part + ((size_t)b * 216 + blockIdx.x) * 456;
        for (int idx = t; idx < 455; idx += 128) pb[idx] = red[idx];
    }
}

__global__ __launch_bounds__(512) void km_update(const float* __restrict__ part, float* __restrict__ cent) {
    __shared__ float cnt_s[NK];
    const int b = blockIdx.x;
    const int t = threadIdx.x;
    const float* pb = part + (size_t)b * 216 * 456;
    if (t < NK) {
        float cn = 0.f;
        for (int p = 0; p < 216; p++) cn += pb[p * 456 + 448 + t];
        cnt_s[t] = cn;
    }
    __syncthreads();
    if (t < 448) {
        float s = 0.f;
        for (int p = 0; p < 216; p++) s += pb[p * 456 + t];
        float cn = cnt_s[t >> 6];
        float oldc = cent[b * 448 + t];
        cent[b * 448 + t] = (cn > 0.f) ? (s / fmaxf(cn, 1.f)) : oldc;
    }
}

// ---------------- centroid MLPs -> WkT[b][k][i][o], bias2[b][k][o] ----------------
__global__ __launch_bounds__(256) void mlp_kernel(const float* __restrict__ cent,
        const float* __restrict__ kW1, const float* __restrict__ kb1,
        const float* __restrict__ kW2, const float* __restrict__ kb2,
        const float* __restrict__ bW1, const float* __restrict__ bb1,
        const float* __restrict__ bW2, const float* __restrict__ bb2,
        const float* __restrict__ w_mat, float* __restrict__ WkT, float* __restrict__ bias2) {
    __shared__ float cr[64];
    __shared__ float hid[256];
    __shared__ float vout[64];
    const int bk = blockIdx.x;            // (b*7 + k)
    const int t = threadIdx.x;
    if (t < 64) cr[t] = cent[bk * 64 + t];
    __syncthreads();
    // kernel branch: sigmoid(relu(c@kW1+kb1)@kW2+kb2)
    float h = kb1[t];
    for (int c = 0; c < 64; c++) h += cr[c] * kW1[c * 256 + t];
    hid[t] = fmaxf(h, 0.f);
    __syncthreads();
    if (t < 64) {
        float s = kb2[t];
        for (int j = 0; j < 256; j++) s += hid[j] * kW2[j * 64 + t];
        vout[t] = 1.f / (1.f + expf(-s));
    }
    __syncthreads();
    for (int idx = t; idx < 4096; idx += 256) {
        int i = idx >> 6, o = idx & 63;
        WkT[(size_t)bk * 4096 + idx] = vout[i] * w_mat[o * 64 + i];
    }
    __syncthreads();
    // bias branch: relu(c@bW1+bb1)@bW2+bb2
    float h2 = bb1[t];
    for (int c = 0; c < 64; c++) h2 += cr[c] * bW1[c * 256 + t];
    hid[t] = fmaxf(h2, 0.f);
    __syncthreads();
    if (t < 64) {
        float s = bb2[t];
        for (int j = 0; j < 256; j++) s += hid[j] * bW2[j * 64 + t];
        bias2[bk * 64 + t] = s;
    }
}

// ---------------- label-gated matvec + bias + shortcut ----------------
// out2[b,o,q] = sum_i WkT[b,lab(q)][i][o] * x1[b,i,q] + bias2[b,lab(q),o] + x1[b,o,q]
__global__ __launch_bounds__(256) void scatter_mm(const float* __restrict__ x1, const int* __restrict__ labels,
                                                  const float* __restrict__ WkT, const float* __restrict__ bias2,
                                                  float* __restrict__ out2) {
    __shared__ float xt[64 * 66];
    __shared__ float os[64 * 66];
    __shared__ int labs[64];
    const int b = blockIdx.y;
    const int q0 = blockIdx.x * 64;
    const int t = threadIdx.x;
    const int lane = t & 63;
    for (int r = t >> 6; r < 64; r += 4)
        xt[r * 66 + lane] = x1[((size_t)b * 64 + r) * QQ + q0 + lane];
    if (t < 64) labs[t] = labels[(size_t)b * QQ + q0 + t];
    __syncthreads();
    const int o = lane;
    const int wq = (t >> 6) * 16;
    for (int qi = 0; qi < 16; qi++) {
        int q = wq + qi;
        int l = labs[q];
        const float* Wp = WkT + ((size_t)(b * 7 + l) << 12);
        float acc = bias2[(b * 7 + l) * 64 + o] + xt[o * 66 + q];
        for (int i = 0; i < 64; i++)
            acc += Wp[i * 64 + o] * xt[i * 66 + q];
        os[o * 66 + q] = acc;
    }
    __syncthreads();
    for (int r = t >> 6; r < 64; r += 4)
        out2[((size_t)b * 64 + r) * QQ + q0 + lane] = os[r * 66 + lane];
}

extern "C" void kernel_launch(void* const* d_in, const int* in_sizes, int n_in,
                              void* d_out, int out_size, void* d_ws, size_t ws_size,
                              hipStream_t stream) {
    const float* x     = (const float*)d_in[0];
    const float* w_in  = (const float*)d_in[1];
    // d_in[2] = b_in : cancelled by InstanceNorm (mean-shift invariance)
    const float* w_mat = (const float*)d_in[3];
    const float* kW1   = (const float*)d_in[4];
    const float* kb1   = (const float*)d_in[5];
    const float* kW2   = (const float*)d_in[6];
    const float* kb2   = (const float*)d_in[7];
    const float* bW1   = (const float*)d_in[8];
    const float* bb1   = (const float*)d_in[9];
    const float* bW2   = (const float*)d_in[10];
    const float* bb2   = (const float*)d_in[11];
    const float* w_out = (const float*)d_in[12];
    // d_in[13] = b_out : cancelled by InstanceNorm
    float* out = (float*)d_out;

    char* ws = (char*)d_ws;
    size_t off = 0;
    auto alloc = [&](size_t bytes) { void* p = ws + off; off = (off + bytes + 255) & ~255UL; return p; };
    float* buf0  = (float*)alloc((size_t)2 * 64 * QQ * 4);     // conv raw / out2
    float* buf1  = (float*)alloc((size_t)2 * 64 * QQ * 4);     // x1 (normed)
    float* w2a   = (float*)alloc(27 * 32 * 64 * 4);
    float* w2b   = (float*)alloc(27 * 64 * 64 * 4);
    float* cent  = (float*)alloc(2 * 448 * 4);
    float* part  = (float*)alloc((size_t)2 * 216 * 456 * 4);
    int*   labels= (int*)  alloc((size_t)2 * QQ * 4);
    float* WkT   = (float*)alloc(2 * 7 * 4096 * 4);
    float* bias2 = (float*)alloc(2 * 448 * 4);
    float2* st   = (float2*)alloc(128 * 8);
    if (off > ws_size) return;  // workspace too small: fail loudly (wrong output) rather than corrupt

    prep_weights<<<648, 256, 0, stream>>>(w_in, w_out, w2a, w2b);
    conv3d_k<32><<<dim3(48, 12, 4), 256, 0, stream>>>(x, w2a, buf0);
    inorm_stats<<<128, 256, 0, stream>>>(buf0, st);
    inorm_apply<<<dim3(108, 128), 256, 0, stream>>>(buf0, st, buf1);

    init_cent<<<4, 256, 0, stream>>>(buf1, cent);
    for (int it = 0; it < 8; it++) {
        km_assign<true><<<dim3(216, 2), 128, 0, stream>>>(buf1, cent, labels, part);
        km_update<<<2, 512, 0, stream>>>(part, cent);
    }
    km_assign<false><<<dim3(216, 2), 128, 0, stream>>>(buf1, cent, labels, nullptr);

    mlp_kernel<<<14, 256, 0, stream>>>(cent, kW1, kb1, kW2, kb2, bW1, bb1, bW2, bb2, w_mat, WkT, bias2);
    scatter_mm<<<dim3(1728, 2), 256, 0, stream>>>(buf1, labels, WkT, bias2, buf0);

    conv3d_k<64><<<dim3(48, 12, 4), 256, 0, stream>>>(buf0, w2b, out);
    inorm_stats<<<128, 256, 0, stream>>>(out, st);
    inorm_apply<<<dim3(108, 128), 256, 0, stream>>>(out, st, out);
}

// Round 3
// 1067.291 us; speedup vs baseline: 2.8097x; 2.0500x over previous
//
#include <hip/hip_runtime.h>

#define DD 48
#define HWQ 2304              // 48*48
#define QQ 110592             // 48^3
#define NK 7

typedef _Float16 f16x8 __attribute__((ext_vector_type(8)));
typedef float f32x16 __attribute__((ext_vector_type(16)));
union U4H8 { uint4 u; f16x8 h; };

// ---------------- x (f32, [b][32][z][y][x]) -> hi/lo fp16 transposed [b][z][y][kg][x][8ch] ----------------
// lo is pre-scaled by 2048 so it stays in fp16 normal range (denorm-proof); conv epilogue divides back.
__global__ __launch_bounds__(256) void transpose_x(const float* __restrict__ x,
                                                   _Float16* __restrict__ xh,
                                                   _Float16* __restrict__ xl) {
    const int hw = blockIdx.x * 256 + threadIdx.x;   // 0..2303
    const int z = blockIdx.y, b = blockIdx.z;
    const int y = hw / 48, xx = hw % 48;
    for (int kg = 0; kg < 4; kg++) {
        U4H8 hi, lo;
        #pragma unroll
        for (int j = 0; j < 8; j++) {
            float v = x[(((size_t)b * 32 + kg * 8 + j) * DD + z) * HWQ + hw];
            _Float16 h = (_Float16)v;
            hi.h[j] = h;
            lo.h[j] = (_Float16)((v - (float)h) * 2048.0f);
        }
        size_t o = ((((size_t)b * DD + z) * 48 + y) * 4 + kg) * 48 + xx;
        ((uint4*)xh)[o] = hi.u;
        ((uint4*)xl)[o] = lo.u;
    }
}

// ---------------- A-fragment prepack: Wp[tap][kstep][ohalf][lane] = 8 fp16 ----------------
// mfma_32x32x16 A layout: lane l holds A[m=l&31][k=(l>>5)*8+j].
// conv1 (K'=96): k' segments [Wh | Wl*2048 | Wh] pairing B segments [Xh ; Xh ; Xl*2048].
__global__ __launch_bounds__(256) void prep_w1(const float* __restrict__ w_in, uint4* __restrict__ Wp) {
    int idx = blockIdx.x * 256 + threadIdx.x;
    if (idx >= 27 * 6 * 2 * 64) return;
    int l = idx & 63; int r = idx >> 6; int oh = r & 1; r >>= 1; int ks = r % 6; int tap = r / 6;
    int o = oh * 32 + (l & 31);
    U4H8 a;
    #pragma unroll
    for (int j = 0; j < 8; j++) {
        int ip = ks * 16 + (l >> 5) * 8 + j;
        _Float16 v;
        if (ip < 32) {
            v = (_Float16)w_in[(o * 32 + ip) * 27 + tap];
        } else if (ip < 64) {
            float w = w_in[(o * 32 + ip - 32) * 27 + tap];
            _Float16 h = (_Float16)w;
            v = (_Float16)((w - (float)h) * 2048.0f);
        } else {
            v = (_Float16)w_in[(o * 32 + ip - 64) * 27 + tap];
        }
        a.h[j] = v;
    }
    Wp[idx] = a.u;
}

__global__ __launch_bounds__(256) void prep_w2(const float* __restrict__ w_out, uint4* __restrict__ Wp) {
    int idx = blockIdx.x * 256 + threadIdx.x;
    if (idx >= 27 * 4 * 2 * 64) return;
    int l = idx & 63; int r = idx >> 6; int oh = r & 1; r >>= 1; int ks = r % 4; int tap = r / 4;
    int o = oh * 32 + (l & 31);
    U4H8 a;
    #pragma unroll
    for (int j = 0; j < 8; j++) {
        int ip = ks * 16 + (l >> 5) * 8 + j;
        a.h[j] = (_Float16)w_out[(o * 64 + ip) * 27 + tap];
    }
    Wp[idx] = a.u;
}

// ---------------- MFMA conv: block = (z, ytile, b), 4 waves = (ohalf, qhalf), 192 pts x 64 o ----------------
// LDS: PLANES x [6y][50x][8ch] fp16 (4800B/plane). B-frag reads: half-wave contiguous 512B, conflict-free.
// SPLIT (conv1): planes 0-3 = Xh, 4-7 = Xl*2048; K'=96 routes passes hi*hi -> accH, cross terms -> accL.
template<int KP, int CINP>
__global__ __launch_bounds__(256) void conv_mfma(const _Float16* __restrict__ src0,
                                                 const _Float16* __restrict__ src1,
                                                 const uint4* __restrict__ Wp,
                                                 float* __restrict__ out) {
    constexpr bool SPLIT = (KP != CINP);
    constexpr int PLANES = SPLIT ? (CINP / 8) * 2 : CINP / 8;   // 8 for both convs
    constexpr int KSTEPS = KP / 16;
    __shared__ char lds[PLANES * 4800];

    const int z = blockIdx.x, ytile = blockIdx.y, b = blockIdx.z;
    const int tid = threadIdx.x;
    const int l = tid & 63;
    const int wv = tid >> 6;
    const int ohalf = wv & 1, qhalf = wv >> 1;

    int vbase[3];
    #pragma unroll
    for (int f = 0; f < 3; f++) {
        int q = qhalf * 96 + f * 32 + (l & 31);
        int yl = q / 48, xl_ = q % 48;
        vbase[f] = (l >> 5) * 4800 + (yl * 50 + xl_) * 16;
    }

    f32x16 accH[3], accL[3];
    #pragma unroll
    for (int f = 0; f < 3; f++)
        #pragma unroll
        for (int rr = 0; rr < 16; rr++) { accH[f][rr] = 0.f; if (SPLIT) accL[f][rr] = 0.f; }

    for (int dz = 0; dz < 3; dz++) {
        int zin = z + dz - 1;
        if (zin < 0 || zin >= DD) continue;         // block-uniform
        __syncthreads();
        for (int idx = tid; idx < PLANES * 300; idx += 256) {
            int p = idx / 300, rem = idx % 300;
            int yy = rem / 50, xs = rem % 50;
            int yg = ytile * 4 + yy - 1, xg = xs - 1;
            uint4 v = make_uint4(0, 0, 0, 0);
            if (yg >= 0 && yg < 48 && xg >= 0 && xg < 48) {
                const _Float16* s = (p < CINP / 8) ? src0 : src1;
                int kg = (p < CINP / 8) ? p : p - CINP / 8;
                v = *(const uint4*)(s + (((((size_t)b * DD + zin) * 48 + yg) * (CINP / 8) + kg) * 48 + xg) * 8);
            }
            *(uint4*)(lds + p * 4800 + (yy * 50 + xs) * 16) = v;
        }
        __syncthreads();

        for (int dy = 0; dy < 3; dy++) {
            for (int dx = 0; dx < 3; dx++) {
                const int tap = (dz * 3 + dy) * 3 + dx;
                const uint4* wp = Wp + ((size_t)(tap * KSTEPS) * 2 + ohalf) * 64 + l;
                const int doff = (dy * 50 + dx) * 16;
                #pragma unroll
                for (int ks = 0; ks < KSTEPS; ks++) {
                    U4H8 a; a.u = wp[ks * 128];
                    const int kgp = ks * 2;
                    const int pl0 = SPLIT ? ((kgp < CINP / 4) ? (kgp & (CINP / 8 - 1)) : (kgp - CINP / 8))
                                          : kgp;
                    const int C = pl0 * 4800 + doff;
                    #pragma unroll
                    for (int f = 0; f < 3; f++) {
                        f16x8 bf = *(const f16x8*)(lds + vbase[f] + C);
                        if constexpr (SPLIT) {
                            if (ks < CINP / 16)
                                accH[f] = __builtin_amdgcn_mfma_f32_32x32x16_f16(a.h, bf, accH[f], 0, 0, 0);
                            else
                                accL[f] = __builtin_amdgcn_mfma_f32_32x32x16_f16(a.h, bf, accL[f], 0, 0, 0);
                        } else {
                            accH[f] = __builtin_amdgcn_mfma_f32_32x32x16_f16(a.h, bf, accH[f], 0, 0, 0);
                        }
                    }
                }
            }
        }
    }

    // D layout (verified): col(q) = l&31, row(o) = (reg&3) + 8*(reg>>2) + 4*(l>>5)
    const size_t obase = (((size_t)b * 64 + ohalf * 32) * DD + z) * HWQ + (size_t)ytile * 192;
    #pragma unroll
    for (int f = 0; f < 3; f++) {
        int q = qhalf * 96 + f * 32 + (l & 31);
        #pragma unroll
        for (int rr = 0; rr < 16; rr++) {
            int row = (rr & 3) + 8 * (rr >> 2) + 4 * (l >> 5);
            float val = accH[f][rr];
            if constexpr (SPLIT) val += accL[f][rr] * (1.0f / 2048.0f);
            out[obase + (size_t)row * QQ + q] = val;
        }
    }
}

// ---------------- InstanceNorm ----------------
__global__ __launch_bounds__(256) void inorm_stats(const float* __restrict__ x, float2* __restrict__ st) {
    __shared__ float ssum[256], ssq[256];
    const int bc = blockIdx.x;
    const float4* p = reinterpret_cast<const float4*>(x + (size_t)bc * QQ);
    float s = 0.f, q2 = 0.f;
    for (int idx = threadIdx.x; idx < QQ / 4; idx += 256) {
        float4 v = p[idx];
        s  += v.x + v.y + v.z + v.w;
        q2 += v.x * v.x + v.y * v.y + v.z * v.z + v.w * v.w;
    }
    ssum[threadIdx.x] = s; ssq[threadIdx.x] = q2;
    __syncthreads();
    for (int off = 128; off > 0; off >>= 1) {
        if (threadIdx.x < off) {
            ssum[threadIdx.x] += ssum[threadIdx.x + off];
            ssq[threadIdx.x]  += ssq[threadIdx.x + off];
        }
        __syncthreads();
    }
    if (threadIdx.x == 0) {
        float mean = ssum[0] / (float)QQ;
        float var = ssq[0] / (float)QQ - mean * mean;
        st[bc] = make_float2(mean, rsqrtf(var + 1e-5f));
    }
}

__global__ __launch_bounds__(256) void inorm_apply(const float* __restrict__ x, const float2* __restrict__ st,
                                                   float* __restrict__ y) {
    const int bc = blockIdx.y;
    float2 mv = st[bc];
    int idx = blockIdx.x * 256 + threadIdx.x;
    float4 v = reinterpret_cast<const float4*>(x + (size_t)bc * QQ)[idx];
    v.x = fmaxf((v.x - mv.x) * mv.y, 0.f);
    v.y = fmaxf((v.y - mv.x) * mv.y, 0.f);
    v.z = fmaxf((v.z - mv.x) * mv.y, 0.f);
    v.w = fmaxf((v.w - mv.x) * mv.y, 0.f);
    reinterpret_cast<float4*>(y + (size_t)bc * QQ)[idx] = v;
}

// ---------------- k-means (numerics identical to round 2) ----------------
__global__ __launch_bounds__(256) void init_cent(const float* __restrict__ x1, float* __restrict__ cent) {
    int t = blockIdx.x * 256 + threadIdx.x;
    if (t < 2 * NK * 64) {
        int b = t / 448, r = t % 448, k = r / 64, c = r % 64;
        cent[t] = x1[((size_t)b * 64 + c) * QQ + k];
    }
}

template<bool WP>
__global__ __launch_bounds__(128) void km_assign(const float* __restrict__ x1, const float* __restrict__ cent,
                                                 int* __restrict__ labels, float* __restrict__ part) {
    __shared__ float tile[64 * 129];
    __shared__ float cs[448];
    __shared__ float c2s[NK];
    __shared__ int labs[128];
    __shared__ float red[456];
    const int b = blockIdx.y;
    const int Q0 = blockIdx.x * 512;
    const int t = threadIdx.x;
    const int c = t & 63, g = t >> 6;

    for (int idx = t; idx < 448; idx += 128) cs[idx] = cent[b * 448 + idx];
    __syncthreads();
    if (t < NK) {
        float s = 0.f;
        for (int ch = 0; ch < 64; ch++) s += cs[t * 64 + ch] * cs[t * 64 + ch];
        c2s[t] = s;
    }

    float ps[NK], pc[NK];
    #pragma unroll
    for (int k = 0; k < NK; k++) { ps[k] = 0.f; pc[k] = 0.f; }

    for (int cc = 0; cc < 4; cc++) {
        const int q0 = Q0 + cc * 128;
        __syncthreads();
        for (int r = 0; r < 64; r++) tile[r * 129 + t] = x1[((size_t)b * 64 + r) * QQ + q0 + t];
        __syncthreads();

        float d[NK];
        #pragma unroll
        for (int k = 0; k < NK; k++) d[k] = 0.f;
        for (int ch = 0; ch < 64; ch++) {
            float xv = tile[ch * 129 + t];
            #pragma unroll
            for (int k = 0; k < NK; k++) d[k] += xv * cs[k * 64 + ch];
        }
        int lab = 0;
        float best = c2s[0] - 2.f * d[0];
        #pragma unroll
        for (int k = 1; k < NK; k++) {
            float dd = c2s[k] - 2.f * d[k];
            if (dd < best) { best = dd; lab = k; }
        }
        labels[(size_t)b * QQ + q0 + t] = lab;

        if (WP) {
            labs[t] = lab;
            __syncthreads();
            for (int j = 0; j < 64; j++) {
                int lb = labs[g * 64 + j];
                float v = tile[c * 129 + g * 64 + j];
                #pragma unroll
                for (int k = 0; k < NK; k++) {
                    ps[k] += (lb == k) ? v : 0.f;
                    pc[k] += (lb == k) ? 1.f : 0.f;
                }
            }
        }
    }

    if (WP) {
        __syncthreads();
        if (g == 0) {
            #pragma unroll
            for (int k = 0; k < NK; k++) red[k * 64 + c] = ps[k];
            if (c == 0) {
                #pragma unroll
                for (int k = 0; k < NK; k++) red[448 + k] = pc[k];
            }
        }
        __syncthreads();
        if (g == 1) {
            #pragma unroll
            for (int k = 0; k < NK; k++) red[k * 64 + c] += ps[k];
            if (c == 0) {
                #pragma unroll
                for (int k = 0; k < NK; k++) red[448 + k] += pc[k];
            }
        }
        __syncthreads();
        float* pb = part + ((size_t)b * 216 + blockIdx.x) * 456;
        for (int idx = t; idx < 455; idx += 128) pb[idx] = red[idx];
    }
}

__global__ __launch_bounds__(512) void km_update(const float* __restrict__ part, float* __restrict__ cent) {
    __shared__ float cnt_s[NK];
    const int b = blockIdx.x;
    const int t = threadIdx.x;
    const float* pb = part + (size_t)b * 216 * 456;
    if (t < NK) {
        float cn = 0.f;
        for (int p = 0; p < 216; p++) cn += pb[p * 456 + 448 + t];
        cnt_s[t] = cn;
    }
    __syncthreads();
    if (t < 448) {
        float s = 0.f;
        for (int p = 0; p < 216; p++) s += pb[p * 456 + t];
        float cn = cnt_s[t >> 6];
        float oldc = cent[b * 448 + t];
        cent[b * 448 + t] = (cn > 0.f) ? (s / fmaxf(cn, 1.f)) : oldc;
    }
}

// ---------------- centroid MLPs -> WkT[b][k][i][o], bias2[b][k][o] ----------------
__global__ __launch_bounds__(256) void mlp_kernel(const float* __restrict__ cent,
        const float* __restrict__ kW1, const float* __restrict__ kb1,
        const float* __restrict__ kW2, const float* __restrict__ kb2,
        const float* __restrict__ bW1, const float* __restrict__ bb1,
        const float* __restrict__ bW2, const float* __restrict__ bb2,
        const float* __restrict__ w_mat, float* __restrict__ WkT, float* __restrict__ bias2) {
    __shared__ float cr[64];
    __shared__ float hid[256];
    __shared__ float vout[64];
    const int bk = blockIdx.x;
    const int t = threadIdx.x;
    if (t < 64) cr[t] = cent[bk * 64 + t];
    __syncthreads();
    float h = kb1[t];
    for (int c = 0; c < 64; c++) h += cr[c] * kW1[c * 256 + t];
    hid[t] = fmaxf(h, 0.f);
    __syncthreads();
    if (t < 64) {
        float s = kb2[t];
        for (int j = 0; j < 256; j++) s += hid[j] * kW2[j * 64 + t];
        vout[t] = 1.f / (1.f + expf(-s));
    }
    __syncthreads();
    for (int idx = t; idx < 4096; idx += 256) {
        int i = idx >> 6, o = idx & 63;
        WkT[(size_t)bk * 4096 + idx] = vout[i] * w_mat[o * 64 + i];
    }
    __syncthreads();
    float h2 = bb1[t];
    for (int c = 0; c < 64; c++) h2 += cr[c] * bW1[c * 256 + t];
    hid[t] = fmaxf(h2, 0.f);
    __syncthreads();
    if (t < 64) {
        float s = bb2[t];
        for (int j = 0; j < 256; j++) s += hid[j] * bW2[j * 64 + t];
        bias2[bk * 64 + t] = s;
    }
}

// ---------------- label-gated matvec + bias + shortcut -> fp16 transposed oT ----------------
__global__ __launch_bounds__(256) void scatter_mm(const float* __restrict__ x1, const int* __restrict__ labels,
                                                  const float* __restrict__ WkT, const float* __restrict__ bias2,
                                                  _Float16* __restrict__ oT) {
    __shared__ float xt[64 * 66];
    __shared__ float os[64 * 66];
    __shared__ int labs[64];
    const int b = blockIdx.y;
    const int q0 = blockIdx.x * 64;
    const int t = threadIdx.x;
    const int lane = t & 63;
    for (int r = t >> 6; r < 64; r += 4)
        xt[r * 66 + lane] = x1[((size_t)b * 64 + r) * QQ + q0 + lane];
    if (t < 64) labs[t] = labels[(size_t)b * QQ + q0 + t];
    __syncthreads();
    const int o = lane;
    const int wq = (t >> 6) * 16;
    for (int qi = 0; qi < 16; qi++) {
        int q = wq + qi;
        int lb = labs[q];
        const float* Wpp = WkT + ((size_t)(b * 7 + lb) << 12);
        float acc = bias2[(b * 7 + lb) * 64 + o] + xt[o * 66 + q];
        for (int i = 0; i < 64; i++)
            acc += Wpp[i * 64 + o] * xt[i * 66 + q];
        os[o * 66 + q] = acc;
    }
    __syncthreads();
    // emit fp16 [b][z][y][kg][x][8]
    {
        int qg = q0 + lane;
        int zz = qg / HWQ; int rem = qg % HWQ; int yy = rem / 48; int xx = rem % 48;
        for (int kg = t >> 6; kg < 8; kg += 4) {
            U4H8 pk;
            #pragma unroll
            for (int j = 0; j < 8; j++) pk.h[j] = (_Float16)os[(kg * 8 + j) * 66 + lane];
            ((uint4*)oT)[((((size_t)b * DD + zz) * 48 + yy) * 8 + kg) * 48 + xx] = pk.u;
        }
    }
}

extern "C" void kernel_launch(void* const* d_in, const int* in_sizes, int n_in,
                              void* d_out, int out_size, void* d_ws, size_t ws_size,
                              hipStream_t stream) {
    const float* x     = (const float*)d_in[0];
    const float* w_in  = (const float*)d_in[1];
    // d_in[2] = b_in : cancelled by InstanceNorm
    const float* w_mat = (const float*)d_in[3];
    const float* kW1   = (const float*)d_in[4];
    const float* kb1   = (const float*)d_in[5];
    const float* kW2   = (const float*)d_in[6];
    const float* kb2   = (const float*)d_in[7];
    const float* bW1   = (const float*)d_in[8];
    const float* bb1   = (const float*)d_in[9];
    const float* bW2   = (const float*)d_in[10];
    const float* bb2   = (const float*)d_in[11];
    const float* w_out = (const float*)d_in[12];
    // d_in[13] = b_out : cancelled by InstanceNorm
    float* out = (float*)d_out;

    char* ws = (char*)d_ws;
    size_t off = 0;
    auto alloc = [&](size_t bytes) { void* p = ws + off; off = (off + bytes + 255) & ~255UL; return p; };
    float*  bufA = (float*)alloc((size_t)2 * 64 * QQ * 4);   // conv1 raw f32; later reused as oT (fp16)
    float*  buf1 = (float*)alloc((size_t)2 * 64 * QQ * 4);   // x1 (normed f32)
    char*   bufB = (char*) alloc((size_t)2 * 2 * 32 * QQ * 2); // xh+xl; later k-means scratch
    uint4*  Wp1  = (uint4*)alloc((size_t)27 * 6 * 2 * 64 * 16);
    uint4*  Wp2  = (uint4*)alloc((size_t)27 * 4 * 2 * 64 * 16);
    float2* st   = (float2*)alloc(128 * 8);
    if (off > ws_size) return;

    _Float16* xh = (_Float16*)bufB;
    _Float16* xl = xh + (size_t)2 * 32 * QQ;
    _Float16* oT = (_Float16*)bufA;
    // post-conv1 aliases into bufB (xh/xl dead once conv1 completes):
    float* part   = (float*)bufB;                       // 788 KB
    int*   labels = (int*)(bufB + (1u << 20));          // 884 KB
    float* WkT    = (float*)(bufB + (2u << 20));        // 229 KB
    float* bias2  = (float*)(bufB + (3u << 20));        // 3.5 KB
    float* cent   = (float*)(bufB + (3u << 20) + 65536);

    transpose_x<<<dim3(9, 48, 2), 256, 0, stream>>>(x, xh, xl);
    prep_w1<<<81, 256, 0, stream>>>(w_in, Wp1);
    prep_w2<<<54, 256, 0, stream>>>(w_out, Wp2);

    conv_mfma<96, 32><<<dim3(48, 12, 2), 256, 0, stream>>>(xh, xl, Wp1, bufA);
    inorm_stats<<<128, 256, 0, stream>>>(bufA, st);
    inorm_apply<<<dim3(108, 128), 256, 0, stream>>>(bufA, st, buf1);

    init_cent<<<4, 256, 0, stream>>>(buf1, cent);
    for (int it = 0; it < 8; it++) {
        km_assign<true><<<dim3(216, 2), 128, 0, stream>>>(buf1, cent, labels, part);
        km_update<<<2, 512, 0, stream>>>(part, cent);
    }
    km_assign<false><<<dim3(216, 2), 128, 0, stream>>>(buf1, cent, labels, nullptr);

    mlp_kernel<<<14, 256, 0, stream>>>(cent, kW1, kb1, kW2, kb2, bW1, bb1, bW2, bb2, w_mat, WkT, bias2);
    scatter_mm<<<dim3(1728, 2), 256, 0, stream>>>(buf1, labels, WkT, bias2, oT);

    conv_mfma<64, 64><<<dim3(48, 12, 2), 256, 0, stream>>>(oT, oT, Wp2, out);
    inorm_stats<<<128, 256, 0, stream>>>(out, st);
    inorm_apply<<<dim3(108, 128), 256, 0, stream>>>(out, st, out);
}